// Round 7
// baseline (212.227 us; speedup 1.0000x reference)
//
#include <hip/hip_runtime.h>

// SupProtoConLoss on MI355X — round 18: supertile L2 locality + fused final.
// League: R16 symmetry 78.9us k_row (total 147.5); R17 3-buf counted-vmcnt
// 81.1us REGRESSED (occupancy 4->3; and per-CU math shows MFMA ~10k cy, LDS
// ~25k cy of 189k: loop is staging-LATENCY bound because concurrent tiles
// per XCD touch 16-32MB of panels >> 4MB L2 -> fills at L3/HBM latency).
// R18 fix 1: supertile remap. Panels grouped 8x8 -> 36 supertiles (diag 36
// tiles, offdiag 64); tiles enumerated supertile-major; each XCD takes a
// contiguous 260-tile chunk (g = (bx&7)*260 + bx>>3). Concurrent working
// set per XCD ~2 supertiles = 16 panels = 2-4MB ⊆ L2; panel chunks fill
// once per supertile, then L2-hit. Loop reverts to R16's winner (2 bufs,
// 32KB, 4 blocks/CU, early-stage + syncthreads drain — now covered).
// R18 fix 2: k_final fused into k_row via last-block-done (threadfence +
// device atomic counter; finisher reads row sums with agent-scope atomic
// loads). 3 launches -> 2 (~61us of non-k_row time in R17's total).

#define NROW 8192
#define DDIM 512
#define NCLS 100
#define TILE 128
#define BK 32
#define NKS 16     // DDIM / BK
#define NTRI 2080  // 64*65/2 tiles; == 8 XCDs * 260

typedef float f32x4 __attribute__((ext_vector_type(4)));
typedef short s16x8 __attribute__((ext_vector_type(8)));

#define GLOBAL_AS __attribute__((address_space(1)))
#define LDS_AS __attribute__((address_space(3)))

__device__ __forceinline__ unsigned short f2bf(float x) {
  unsigned int u = __builtin_bit_cast(unsigned int, x);
  u += 0x7FFFu + ((u >> 16) & 1u);  // round-to-nearest-even
  return (unsigned short)(u >> 16);
}

// One wave per row: L2-norm, scale, cast to bf16. Also zeroes row_pos/row_neg
// and the done-counter — k_row only touches them afterwards.
__global__ void __launch_bounds__(256) k_prep(
    const float* __restrict__ reps, float* __restrict__ row_pos,
    unsigned short* __restrict__ Rb, unsigned* __restrict__ cnt) {
  const int wave = threadIdx.x >> 6;
  const int lane = threadIdx.x & 63;
  const int row = blockIdx.x * 4 + wave;
  if (threadIdx.x < 8) row_pos[blockIdx.x * 8 + threadIdx.x] = 0.0f;
  if (blockIdx.x == 0 && threadIdx.x == 0) cnt[0] = 0u;
  const float* r = reps + (size_t)row * DDIM;
  float4 v0 = *(const float4*)(r + lane * 4);
  float4 v1 = *(const float4*)(r + 256 + lane * 4);
  float ss = v0.x * v0.x + v0.y * v0.y + v0.z * v0.z + v0.w * v0.w +
             v1.x * v1.x + v1.y * v1.y + v1.z * v1.z + v1.w * v1.w;
#pragma unroll
  for (int m = 1; m < 64; m <<= 1) ss += __shfl_xor(ss, m);
  const float scale = 1.0f / sqrtf(ss);  // norms ~22.6; 1e-8 clamp unreachable
  ushort4 a, b;
  a.x = f2bf(v0.x * scale); a.y = f2bf(v0.y * scale);
  a.z = f2bf(v0.z * scale); a.w = f2bf(v0.w * scale);
  b.x = f2bf(v1.x * scale); b.y = f2bf(v1.y * scale);
  b.z = f2bf(v1.z * scale); b.w = f2bf(v1.w * scale);
  *(ushort4*)(Rb + (size_t)row * DDIM + lane * 4) = a;
  *(ushort4*)(Rb + (size_t)row * DDIM + 256 + lane * 4) = b;
}

// Block = one upper-triangle 128x128 tile (tm <= tn), chosen by supertile-
// major enumeration chunked per XCD. 4 waves as 2M x 2N; wave tile 64x64 =
// acc[4][4] of 16x16x32. LDS [buf2][mat][row][BK], row stride 64 B; 16B slot
// s of row r stored at phys slot s^(r&3) (staged + read with the same XOR).
__global__ void __launch_bounds__(256, 4) k_row(
    const unsigned short* __restrict__ Rb, const int* __restrict__ labels,
    float* __restrict__ row_pos, float* __restrict__ row_neg,
    unsigned* __restrict__ cnt, float* __restrict__ out) {
  const int bx = blockIdx.x;
  // ---- supertile-major tile id: per-XCD contiguous 260-chunk.
  const int g = (bx & 7) * (NTRI / 8) + (bx >> 3);
  int rem = g, TM = 0, TN = 0;
  bool fnd = false;
  for (int tn_ = 0; tn_ < 8 && !fnd; ++tn_)
    for (int tm_ = 0; tm_ <= tn_ && !fnd; ++tm_) {
      const int c = (tm_ == tn_) ? 36 : 64;
      if (rem < c) { TM = tm_; TN = tn_; fnd = true; }
      else rem -= c;
    }
  int lm, ln;
  if (TM == TN) {  // decode triangle index rem in [0,36) -> lm <= ln
    ln = 0;
    while ((ln + 1) * (ln + 2) / 2 <= rem) ++ln;
    lm = rem - ln * (ln + 1) / 2;
  } else {
    lm = rem >> 3; ln = rem & 7;
  }
  const int tm = TM * 8 + lm, tn = TN * 8 + ln;  // tm <= tn
  const int i0 = tm * TILE;
  const int j0 = tn * TILE;
  const bool diag = (tm == tn);

  __shared__ __attribute__((aligned(16))) unsigned short LDSH[2][2][TILE][BK];
  unsigned short* LF = &LDSH[0][0][0][0];

  const int tid = threadIdx.x;
  const int lane = tid & 63;
  const int wave = tid >> 6;  // 0..3
  const int wr = wave >> 1, wc = wave & 1;
  const int quad = lane >> 4, c16 = lane & 15;

  // Staging: unit u (16B) -> LDS offset u*16 (linear dest); row = u>>2,
  // phys slot = u&3 -> source slot (u&3)^(row&3) (pre-permuted source).
  unsigned sb[2][2];  // [mat][t] per-lane source base (shorts)
#pragma unroll
  for (int mt = 0; mt < 2; ++mt) {
    const int r0 = mt ? j0 : i0;
#pragma unroll
    for (int tt = 0; tt < 2; ++tt) {
      const unsigned u = wave * 128 + tt * 64 + lane;
      sb[mt][tt] =
          (unsigned)(r0 + (u >> 2)) * DDIM + (((u & 3) ^ ((u >> 2) & 3)) * 8);
    }
  }

  auto stage = [&](int kt, int bb) {
    const int koff = kt * BK;
#pragma unroll
    for (int mt = 0; mt < 2; ++mt)
#pragma unroll
      for (int tt = 0; tt < 2; ++tt) {
        const unsigned short* src = Rb + sb[mt][tt] + koff;
        __builtin_amdgcn_global_load_lds(
            (GLOBAL_AS void*)const_cast<unsigned short*>(src),
            (LDS_AS void*)(LF + bb * 8192 + mt * 4096 +
                           (wave * 128 + tt * 64) * 8),
            16, 0, 0);
      }
  };

  // Frag read bases (shorts). row&3 == c16&3 for all m/n -> xslot hoists.
  const int xs = (quad ^ (c16 & 3)) * 8;
  const int aBase = (wr * 64 + c16) * 32 + xs;
  const int bBase = 4096 + (wc * 64 + c16) * 32 + xs;

  f32x4 acc[4][4];
#pragma unroll
  for (int m = 0; m < 4; ++m)
#pragma unroll
    for (int n = 0; n < 4; ++n) acc[m][n] = (f32x4)0.0f;

  stage(0, 0);
  __syncthreads();

#pragma unroll 2
  for (int kt = 0; kt < NKS; ++kt) {
    const int cur = kt & 1;
    if (kt < NKS - 1) stage(kt + 1, cur ^ 1);  // early issue: ~full iter to land
    const int cb = cur * 8192;
    s16x8 af[4], bf[4];
#pragma unroll
    for (int m = 0; m < 4; ++m)
      af[m] = *(const s16x8*)(LF + cb + aBase + m * 512);
#pragma unroll
    for (int n = 0; n < 4; ++n)
      bf[n] = *(const s16x8*)(LF + cb + bBase + n * 512);
#pragma unroll
    for (int m = 0; m < 4; ++m)
#pragma unroll
      for (int n = 0; n < 4; ++n)
        acc[m][n] = __builtin_amdgcn_mfma_f32_16x16x32_bf16(af[m], bf[n],
                                                            acc[m][n], 0, 0, 0);
    __syncthreads();  // drains stage(kt+1) DMAs (L2-hit: covered) + buf swap
  }

  // ---- Epilogue: fold tile into row-i sums and (off-diag) row-j sums.
  float* rp = (float*)(void*)LF;  // 128 rpos | 128 rneg | 128 cpos | 128 cneg
  float* rn = rp + 128;
  float* cp = rn + 128;
  float* cn = cp + 128;
  rp[tid] = 0.0f;
  rp[tid + 256] = 0.0f;
  __syncthreads();

  const float C0 = -5.0f + 1e-7f;  // s = 5g - 5 + 1e-7 (static shift S=10)
  int lj4[4], gj4[4];
#pragma unroll
  for (int n = 0; n < 4; ++n) {
    gj4[n] = j0 + wc * 64 + n * 16 + c16;
    lj4[n] = labels[gj4[n]];
  }
  float psj[4] = {0.0f, 0.0f, 0.0f, 0.0f};
  float nsj[4] = {0.0f, 0.0f, 0.0f, 0.0f};
#pragma unroll
  for (int m = 0; m < 4; ++m) {
#pragma unroll
    for (int r = 0; r < 4; ++r) {
      const int lrow = wr * 64 + m * 16 + quad * 4 + r;
      const int gi = i0 + lrow;
      const int li = labels[gi];
      float psi = 0.0f, nsi = 0.0f;
#pragma unroll
      for (int n = 0; n < 4; ++n) {
        const float g2 = acc[m][n][r];
        const float sv = fmaf(g2, 5.0f, C0);
        const float ev = __expf(sv);
        const bool same = (li == lj4[n]);
        const bool ok = same && (gi != gj4[n]);
        psi += ok ? sv : 0.0f;
        nsi += same ? 0.0f : ev;
        psj[n] += ok ? sv : 0.0f;  // col-side accumulation (over m,r)
        nsj[n] += same ? 0.0f : ev;
      }
#pragma unroll
      for (int s = 1; s < 16; s <<= 1) {  // reduce over the 16 c16 lanes
        psi += __shfl_xor(psi, s);
        nsi += __shfl_xor(nsi, s);
      }
      if (c16 == 0) {
        atomicAdd(&rp[lrow], psi);
        atomicAdd(&rn[lrow], nsi);
      }
    }
  }
  if (!diag) {  // col-side: reduce over quad groups, cross-wr via LDS atomics
#pragma unroll
    for (int n = 0; n < 4; ++n) {
      float p = psj[n], q = nsj[n];
      p += __shfl_xor(p, 16); p += __shfl_xor(p, 32);
      q += __shfl_xor(q, 16); q += __shfl_xor(q, 32);
      if (quad == 0) {
        atomicAdd(&cp[wc * 64 + n * 16 + c16], p);
        atomicAdd(&cn[wc * 64 + n * 16 + c16], q);
      }
    }
  }
  __syncthreads();
  if (tid < 128) {
    atomicAdd(&row_pos[i0 + tid], rp[tid]);
    atomicAdd(&row_neg[i0 + tid], rn[tid]);
  } else if (!diag) {
    atomicAdd(&row_pos[j0 + tid - 128], cp[tid - 128]);
    atomicAdd(&row_neg[j0 + tid - 128], cn[tid - 128]);
  }
  __syncthreads();  // all this block's global atomics retired (vmcnt drained)

  // ---- last-block-done: the final block folds the loss (fused k_final).
  unsigned* flg = (unsigned*)(void*)LF + 600;  // outside the [0,512) floats
  if (tid == 0) {
    __threadfence();
    flg[0] = atomicAdd(cnt, 1u);
  }
  __syncthreads();
  if (flg[0] != NTRI - 1) return;

  int* hcnt = (int*)(void*)LF;  // reuse LDS: 100 ints
  float* fs = (float*)(void*)LF + 128;
  float* fc = fs + 8;
  if (tid < NCLS) hcnt[tid] = 0;
  __syncthreads();
  for (int i = tid; i < NROW; i += 256) atomicAdd(&hcnt[labels[i]], 1);
  __syncthreads();
  float lsum = 0.0f, lcnt = 0.0f;
  for (int i = tid; i < NROW; i += 256) {
    const float c = (float)(hcnt[labels[i]] - 1);
    const float rp_ = __hip_atomic_load(&row_pos[i], __ATOMIC_RELAXED,
                                        __HIP_MEMORY_SCOPE_AGENT);
    const float rn_ = __hip_atomic_load(&row_neg[i], __ATOMIC_RELAXED,
                                        __HIP_MEMORY_SCOPE_AGENT);
    const float pos = rp_ / (c + 1e-8f);
    const float loss = -pos + logf(rn_ + 1e-8f);
    if (loss > 0.0f) { lsum += loss; lcnt += 1.0f; }
  }
#pragma unroll
  for (int m = 1; m < 64; m <<= 1) {
    lsum += __shfl_xor(lsum, m);
    lcnt += __shfl_xor(lcnt, m);
  }
  if (lane == 0) { fs[wave] = lsum; fc[wave] = lcnt; }
  __syncthreads();
  if (tid == 0) {
    float S = 0.0f, C = 0.0f;
#pragma unroll
    for (int w = 0; w < 4; ++w) { S += fs[w]; C += fc[w]; }
    out[0] = S / (C + 1e-8f);
  }
}

extern "C" void kernel_launch(void* const* d_in, const int* in_sizes, int n_in,
                              void* d_out, int out_size, void* d_ws, size_t ws_size,
                              hipStream_t stream) {
  const float* reps = (const float*)d_in[0];
  const int* labels = (const int*)d_in[1];
  float* out = (float*)d_out;
  char* ws = (char*)d_ws;
  // ws layout: Rb (bf16 normalized reps, 8 MiB) | row_pos | row_neg | cnt
  unsigned short* Rb = (unsigned short*)ws;
  float* row_pos = (float*)(ws + (size_t)NROW * DDIM * 2);
  float* row_neg = row_pos + NROW;
  unsigned* cnt = (unsigned*)(row_neg + NROW);

  k_prep<<<NROW / 4, 256, 0, stream>>>(reps, row_pos, Rb, cnt);
  k_row<<<NTRI, 256, 0, stream>>>(Rb, labels, row_pos, row_neg, cnt, out);
  (void)in_sizes; (void)n_in; (void)out_size; (void)ws_size;
}

// Round 8
// 161.646 us; speedup vs baseline: 1.3129x; 1.3129x over previous
//
#include <hip/hip_runtime.h>

// SupProtoConLoss on MI355X — round 19: R18 minus __threadfence (1-var test).
// League: R16 symmetry 78.9us k_row; R17 3-buf 81.1 (regress); R18 supertile
// remap + fused finisher 152us REGRESSED 2x. Diagnosis: per-block
// __threadfence = L2 writeback-invalidate x2080 -> destroys the L2 panel
// residency the remap bought (staging falls to L3 latency; FETCH stayed low
// because L3 refills don't count as HBM fetch). The fence is also
// unnecessary: row_pos/row_neg are produced by device-scope atomicAdd
// (coherence-point RMW — required anyway for cross-XCD concurrent adds), and
// __syncthreads' vmcnt(0) waits their completion acks => globally visible
// before the cnt increment issues. Finisher reads via agent-scope atomic
// loads. R19 drops the fence, keeps: supertile remap (FETCH 96->40MB,
// verified), R16 loop (2-buf, 32KB, 4 blocks/CU), fused last-block finisher.

#define NROW 8192
#define DDIM 512
#define NCLS 100
#define TILE 128
#define BK 32
#define NKS 16     // DDIM / BK
#define NTRI 2080  // 64*65/2 tiles; == 8 XCDs * 260

typedef float f32x4 __attribute__((ext_vector_type(4)));
typedef short s16x8 __attribute__((ext_vector_type(8)));

#define GLOBAL_AS __attribute__((address_space(1)))
#define LDS_AS __attribute__((address_space(3)))

__device__ __forceinline__ unsigned short f2bf(float x) {
  unsigned int u = __builtin_bit_cast(unsigned int, x);
  u += 0x7FFFu + ((u >> 16) & 1u);  // round-to-nearest-even
  return (unsigned short)(u >> 16);
}

// One wave per row: L2-norm, scale, cast to bf16. Also zeroes row_pos/row_neg
// and the done-counter — k_row only touches them afterwards.
__global__ void __launch_bounds__(256) k_prep(
    const float* __restrict__ reps, float* __restrict__ row_pos,
    unsigned short* __restrict__ Rb, unsigned* __restrict__ cnt) {
  const int wave = threadIdx.x >> 6;
  const int lane = threadIdx.x & 63;
  const int row = blockIdx.x * 4 + wave;
  if (threadIdx.x < 8) row_pos[blockIdx.x * 8 + threadIdx.x] = 0.0f;
  if (blockIdx.x == 0 && threadIdx.x == 0) cnt[0] = 0u;
  const float* r = reps + (size_t)row * DDIM;
  float4 v0 = *(const float4*)(r + lane * 4);
  float4 v1 = *(const float4*)(r + 256 + lane * 4);
  float ss = v0.x * v0.x + v0.y * v0.y + v0.z * v0.z + v0.w * v0.w +
             v1.x * v1.x + v1.y * v1.y + v1.z * v1.z + v1.w * v1.w;
#pragma unroll
  for (int m = 1; m < 64; m <<= 1) ss += __shfl_xor(ss, m);
  const float scale = 1.0f / sqrtf(ss);  // norms ~22.6; 1e-8 clamp unreachable
  ushort4 a, b;
  a.x = f2bf(v0.x * scale); a.y = f2bf(v0.y * scale);
  a.z = f2bf(v0.z * scale); a.w = f2bf(v0.w * scale);
  b.x = f2bf(v1.x * scale); b.y = f2bf(v1.y * scale);
  b.z = f2bf(v1.z * scale); b.w = f2bf(v1.w * scale);
  *(ushort4*)(Rb + (size_t)row * DDIM + lane * 4) = a;
  *(ushort4*)(Rb + (size_t)row * DDIM + 256 + lane * 4) = b;
}

// Block = one upper-triangle 128x128 tile (tm <= tn), chosen by supertile-
// major enumeration chunked per XCD. 4 waves as 2M x 2N; wave tile 64x64 =
// acc[4][4] of 16x16x32. LDS [buf2][mat][row][BK], row stride 64 B; 16B slot
// s of row r stored at phys slot s^(r&3) (staged + read with the same XOR).
__global__ void __launch_bounds__(256, 4) k_row(
    const unsigned short* __restrict__ Rb, const int* __restrict__ labels,
    float* __restrict__ row_pos, float* __restrict__ row_neg,
    unsigned* __restrict__ cnt, float* __restrict__ out) {
  const int bx = blockIdx.x;
  // ---- supertile-major tile id: per-XCD contiguous 260-chunk.
  const int g = (bx & 7) * (NTRI / 8) + (bx >> 3);
  int rem = g, TM = 0, TN = 0;
  bool fnd = false;
  for (int tn_ = 0; tn_ < 8 && !fnd; ++tn_)
    for (int tm_ = 0; tm_ <= tn_ && !fnd; ++tm_) {
      const int c = (tm_ == tn_) ? 36 : 64;
      if (rem < c) { TM = tm_; TN = tn_; fnd = true; }
      else rem -= c;
    }
  int lm, ln;
  if (TM == TN) {  // decode triangle index rem in [0,36) -> lm <= ln
    ln = 0;
    while ((ln + 1) * (ln + 2) / 2 <= rem) ++ln;
    lm = rem - ln * (ln + 1) / 2;
  } else {
    lm = rem >> 3; ln = rem & 7;
  }
  const int tm = TM * 8 + lm, tn = TN * 8 + ln;  // tm <= tn
  const int i0 = tm * TILE;
  const int j0 = tn * TILE;
  const bool diag = (tm == tn);

  __shared__ __attribute__((aligned(16))) unsigned short LDSH[2][2][TILE][BK];
  unsigned short* LF = &LDSH[0][0][0][0];

  const int tid = threadIdx.x;
  const int lane = tid & 63;
  const int wave = tid >> 6;  // 0..3
  const int wr = wave >> 1, wc = wave & 1;
  const int quad = lane >> 4, c16 = lane & 15;

  // Staging: unit u (16B) -> LDS offset u*16 (linear dest); row = u>>2,
  // phys slot = u&3 -> source slot (u&3)^(row&3) (pre-permuted source).
  unsigned sb[2][2];  // [mat][t] per-lane source base (shorts)
#pragma unroll
  for (int mt = 0; mt < 2; ++mt) {
    const int r0 = mt ? j0 : i0;
#pragma unroll
    for (int tt = 0; tt < 2; ++tt) {
      const unsigned u = wave * 128 + tt * 64 + lane;
      sb[mt][tt] =
          (unsigned)(r0 + (u >> 2)) * DDIM + (((u & 3) ^ ((u >> 2) & 3)) * 8);
    }
  }

  auto stage = [&](int kt, int bb) {
    const int koff = kt * BK;
#pragma unroll
    for (int mt = 0; mt < 2; ++mt)
#pragma unroll
      for (int tt = 0; tt < 2; ++tt) {
        const unsigned short* src = Rb + sb[mt][tt] + koff;
        __builtin_amdgcn_global_load_lds(
            (GLOBAL_AS void*)const_cast<unsigned short*>(src),
            (LDS_AS void*)(LF + bb * 8192 + mt * 4096 +
                           (wave * 128 + tt * 64) * 8),
            16, 0, 0);
      }
  };

  // Frag read bases (shorts). row&3 == c16&3 for all m/n -> xslot hoists.
  const int xs = (quad ^ (c16 & 3)) * 8;
  const int aBase = (wr * 64 + c16) * 32 + xs;
  const int bBase = 4096 + (wc * 64 + c16) * 32 + xs;

  f32x4 acc[4][4];
#pragma unroll
  for (int m = 0; m < 4; ++m)
#pragma unroll
    for (int n = 0; n < 4; ++n) acc[m][n] = (f32x4)0.0f;

  stage(0, 0);
  __syncthreads();

#pragma unroll 2
  for (int kt = 0; kt < NKS; ++kt) {
    const int cur = kt & 1;
    if (kt < NKS - 1) stage(kt + 1, cur ^ 1);  // early issue: ~full iter to land
    const int cb = cur * 8192;
    s16x8 af[4], bf[4];
#pragma unroll
    for (int m = 0; m < 4; ++m)
      af[m] = *(const s16x8*)(LF + cb + aBase + m * 512);
#pragma unroll
    for (int n = 0; n < 4; ++n)
      bf[n] = *(const s16x8*)(LF + cb + bBase + n * 512);
#pragma unroll
    for (int m = 0; m < 4; ++m)
#pragma unroll
      for (int n = 0; n < 4; ++n)
        acc[m][n] = __builtin_amdgcn_mfma_f32_16x16x32_bf16(af[m], bf[n],
                                                            acc[m][n], 0, 0, 0);
    __syncthreads();  // drains stage(kt+1) DMAs (L2-hit: covered) + buf swap
  }

  // ---- Epilogue: fold tile into row-i sums and (off-diag) row-j sums.
  float* rp = (float*)(void*)LF;  // 128 rpos | 128 rneg | 128 cpos | 128 cneg
  float* rn = rp + 128;
  float* cp = rn + 128;
  float* cn = cp + 128;
  rp[tid] = 0.0f;
  rp[tid + 256] = 0.0f;
  __syncthreads();

  const float C0 = -5.0f + 1e-7f;  // s = 5g - 5 + 1e-7 (static shift S=10)
  int lj4[4], gj4[4];
#pragma unroll
  for (int n = 0; n < 4; ++n) {
    gj4[n] = j0 + wc * 64 + n * 16 + c16;
    lj4[n] = labels[gj4[n]];
  }
  float psj[4] = {0.0f, 0.0f, 0.0f, 0.0f};
  float nsj[4] = {0.0f, 0.0f, 0.0f, 0.0f};
#pragma unroll
  for (int m = 0; m < 4; ++m) {
#pragma unroll
    for (int r = 0; r < 4; ++r) {
      const int lrow = wr * 64 + m * 16 + quad * 4 + r;
      const int gi = i0 + lrow;
      const int li = labels[gi];
      float psi = 0.0f, nsi = 0.0f;
#pragma unroll
      for (int n = 0; n < 4; ++n) {
        const float g2 = acc[m][n][r];
        const float sv = fmaf(g2, 5.0f, C0);
        const float ev = __expf(sv);
        const bool same = (li == lj4[n]);
        const bool ok = same && (gi != gj4[n]);
        psi += ok ? sv : 0.0f;
        nsi += same ? 0.0f : ev;
        psj[n] += ok ? sv : 0.0f;  // col-side accumulation (over m,r)
        nsj[n] += same ? 0.0f : ev;
      }
#pragma unroll
      for (int s = 1; s < 16; s <<= 1) {  // reduce over the 16 c16 lanes
        psi += __shfl_xor(psi, s);
        nsi += __shfl_xor(nsi, s);
      }
      if (c16 == 0) {
        atomicAdd(&rp[lrow], psi);
        atomicAdd(&rn[lrow], nsi);
      }
    }
  }
  if (!diag) {  // col-side: reduce over quad groups, cross-wr via LDS atomics
#pragma unroll
    for (int n = 0; n < 4; ++n) {
      float p = psj[n], q = nsj[n];
      p += __shfl_xor(p, 16); p += __shfl_xor(p, 32);
      q += __shfl_xor(q, 16); q += __shfl_xor(q, 32);
      if (quad == 0) {
        atomicAdd(&cp[wc * 64 + n * 16 + c16], p);
        atomicAdd(&cn[wc * 64 + n * 16 + c16], q);
      }
    }
  }
  __syncthreads();
  if (tid < 128) {
    atomicAdd(&row_pos[i0 + tid], rp[tid]);
    atomicAdd(&row_neg[i0 + tid], rn[tid]);
  } else if (!diag) {
    atomicAdd(&row_pos[j0 + tid - 128], cp[tid - 128]);
    atomicAdd(&row_neg[j0 + tid - 128], cn[tid - 128]);
  }
  __syncthreads();  // emits s_waitcnt vmcnt(0): all row atomics ACKED at the
                    // coherence point (they're device-scope RMWs) => globally
                    // visible. NO cache-flushing fence needed (R18's mistake).

  // ---- last-block-done: the final block folds the loss (fused k_final).
  unsigned* flg = (unsigned*)(void*)LF + 600;  // outside the [0,512) floats
  if (tid == 0) {
    asm volatile("s_waitcnt vmcnt(0)" ::: "memory");  // belt-and-braces
    flg[0] = atomicAdd(cnt, 1u);
  }
  __syncthreads();
  if (flg[0] != NTRI - 1) return;

  int* hcnt = (int*)(void*)LF;  // reuse LDS: 100 ints
  float* fs = (float*)(void*)LF + 128;
  float* fc = fs + 8;
  if (tid < NCLS) hcnt[tid] = 0;
  __syncthreads();
  for (int i = tid; i < NROW; i += 256) atomicAdd(&hcnt[labels[i]], 1);
  __syncthreads();
  float lsum = 0.0f, lcnt = 0.0f;
  for (int i = tid; i < NROW; i += 256) {
    const float c = (float)(hcnt[labels[i]] - 1);
    const float rp_ = __hip_atomic_load(&row_pos[i], __ATOMIC_RELAXED,
                                        __HIP_MEMORY_SCOPE_AGENT);
    const float rn_ = __hip_atomic_load(&row_neg[i], __ATOMIC_RELAXED,
                                        __HIP_MEMORY_SCOPE_AGENT);
    const float pos = rp_ / (c + 1e-8f);
    const float loss = -pos + logf(rn_ + 1e-8f);
    if (loss > 0.0f) { lsum += loss; lcnt += 1.0f; }
  }
#pragma unroll
  for (int m = 1; m < 64; m <<= 1) {
    lsum += __shfl_xor(lsum, m);
    lcnt += __shfl_xor(lcnt, m);
  }
  if (lane == 0) { fs[wave] = lsum; fc[wave] = lcnt; }
  __syncthreads();
  if (tid == 0) {
    float S = 0.0f, C = 0.0f;
#pragma unroll
    for (int w = 0; w < 4; ++w) { S += fs[w]; C += fc[w]; }
    out[0] = S / (C + 1e-8f);
  }
}

extern "C" void kernel_launch(void* const* d_in, const int* in_sizes, int n_in,
                              void* d_out, int out_size, void* d_ws, size_t ws_size,
                              hipStream_t stream) {
  const float* reps = (const float*)d_in[0];
  const int* labels = (const int*)d_in[1];
  float* out = (float*)d_out;
  char* ws = (char*)d_ws;
  // ws layout: Rb (bf16 normalized reps, 8 MiB) | row_pos | row_neg | cnt
  unsigned short* Rb = (unsigned short*)ws;
  float* row_pos = (float*)(ws + (size_t)NROW * DDIM * 2);
  float* row_neg = row_pos + NROW;
  unsigned* cnt = (unsigned*)(row_neg + NROW);

  k_prep<<<NROW / 4, 256, 0, stream>>>(reps, row_pos, Rb, cnt);
  k_row<<<NTRI, 256, 0, stream>>>(Rb, labels, row_pos, row_neg, cnt, out);
  (void)in_sizes; (void)n_in; (void)out_size; (void)ws_size;
}